// Round 2
// baseline (168.289 us; speedup 1.0000x reference)
//
#include <hip/hip_runtime.h>
#include <hip/hip_cooperative_groups.h>
#include <math.h>

#define D 256
#define Q 256
#define I 2048

namespace cg = cooperative_groups;

typedef __attribute__((ext_vector_type(8))) short short8;
typedef __attribute__((ext_vector_type(4))) float floatx4;

__device__ __forceinline__ float wave_sum(float v) {
#pragma unroll
    for (int off = 1; off < 64; off <<= 1)
        v += __shfl_xor(v, off, 64);
    return v;
}

__device__ __forceinline__ float sigmoidf_(float x) {
    return 1.0f / (1.0f + expf(-x));
}

// fp32 -> bf16 round-to-nearest-even
__device__ __forceinline__ unsigned short f2bf(float f) {
    unsigned u = __float_as_uint(f);
    u += 0x7FFFu + ((u >> 16) & 1u);
    return (unsigned short)(u >> 16);
}

// Single cooperative kernel: phase A (prep) -> grid.sync -> phase B (MFMA).
// 1024 blocks x 64 threads (1 wave/block, ~4 waves/CU -> co-resident).
//
// Phase A: block b normalizes gallery rows 2b, 2b+1 -> bf16 Y, Y^2.
//          blocks b<256 additionally run the full query math for q=b
//          (bit-identical to the previous passing query_prep wave code).
// Phase B: block b -> (q-tile b&15, i-tile b>>4); wave = 16q x 32i, K=256.
//   acc1[i,q] = sum_k Y[i,k]  * P[q,k]
//   acc2[i,q] = sum_k Y2[i,k] * W[q,k] + Y[i,k] * V[q,k]
// All operands bf16, L2-resident (~3.4 MB). No LDS, no __syncthreads.
__global__ void __launch_bounds__(64)
gfn_fused(const float* __restrict__ qf,
          const float* __restrict__ qif,
          const float* __restrict__ gal,
          const float* __restrict__ gamma,
          const float* __restrict__ beta,
          const float* __restrict__ mean,
          const float* __restrict__ var,
          unsigned short* __restrict__ PB,
          unsigned short* __restrict__ WB,
          unsigned short* __restrict__ VB,
          unsigned short* __restrict__ YB,
          unsigned short* __restrict__ Y2B,
          float* __restrict__ sq,
          float* __restrict__ ccp,
          float* __restrict__ out) {
    const int b = blockIdx.x;
    const int l = threadIdx.x;   // one wave per block

    // ================= Phase A: prep =================
    // ---- gallery: 2 rows per block; lane holds d = 4l..4l+3 ----
#pragma unroll
    for (int r = 0; r < 2; r++) {
        const int i = b * 2 + r;
        float4 x = ((const float4*)gal)[(size_t)i * 64 + l];
        float n = wave_sum(x.x * x.x + x.y * x.y + x.z * x.z + x.w * x.w);
        float inv = 1.0f / fmaxf(sqrtf(n), 1e-12f);
        float y0 = x.x * inv, y1 = x.y * inv, y2 = x.z * inv, y3 = x.w * inv;
        *(ushort4*)&YB[(size_t)i * D + 4 * l] =
            make_ushort4(f2bf(y0), f2bf(y1), f2bf(y2), f2bf(y3));
        *(ushort4*)&Y2B[(size_t)i * D + 4 * l] =
            make_ushort4(f2bf(y0 * y0), f2bf(y1 * y1), f2bf(y2 * y2), f2bf(y3 * y3));
    }

    // ---- query: blocks [0,256) handle q = b (unchanged math) ----
    if (b < Q) {
        const int q = b;
        const float4* qf4  = (const float4*)qf;
        const float4* qif4 = (const float4*)qif;
        const float4* ga4  = (const float4*)gamma;
        const float4* be4  = (const float4*)beta;
        const float4* me4  = (const float4*)mean;
        const float4* va4  = (const float4*)var;

        float4 x = qf4[(size_t)q * 64 + l];
        float nx = wave_sum(x.x * x.x + x.y * x.y + x.z * x.z + x.w * x.w);
        float inx = 1.0f / fmaxf(sqrtf(nx), 1e-12f);
        float g0 = sigmoidf_(x.x * inx * 5.0f);
        float g1 = sigmoidf_(x.y * inx * 5.0f);
        float g2 = sigmoidf_(x.z * inx * 5.0f);
        float g3 = sigmoidf_(x.w * inx * 5.0f);

        float4 y = qif4[(size_t)q * 64 + l];
        float ny = wave_sum(y.x * y.x + y.y * y.y + y.z * y.z + y.w * y.w);
        float iny = 1.0f / fmaxf(sqrtf(ny), 1e-12f);

        float4 gm = ga4[l], bt = be4[l], mn = me4[l], vr = va4[l];
        float is0 = gm.x * rsqrtf(vr.x + 1e-5f);
        float is1 = gm.y * rsqrtf(vr.y + 1e-5f);
        float is2 = gm.z * rsqrtf(vr.z + 1e-5f);
        float is3 = gm.w * rsqrtf(vr.w + 1e-5f);
        float c0 = bt.x - mn.x * is0;
        float c1 = bt.y - mn.y * is1;
        float c2 = bt.z - mn.z * is2;
        float c3 = bt.w - mn.w * is3;
        float a0 = g0 * is0, a1 = g1 * is1, a2 = g2 * is2, a3 = g3 * is3;

        float f0 = y.x * iny * a0 + c0;
        float f1 = y.y * iny * a1 + c1;
        float f2 = y.z * iny * a2 + c2;
        float f3 = y.w * iny * a3 + c3;
        float nf = wave_sum(f0 * f0 + f1 * f1 + f2 * f2 + f3 * f3);
        float inf_ = 1.0f / fmaxf(sqrtf(nf), 1e-12f);
        float u0 = f0 * inf_, u1 = f1 * inf_, u2 = f2 * inf_, u3 = f3 * inf_;

        *(ushort4*)&PB[(size_t)q * D + 4 * l] =
            make_ushort4(f2bf(u0 * a0), f2bf(u1 * a1), f2bf(u2 * a2), f2bf(u3 * a3));
        *(ushort4*)&WB[(size_t)q * D + 4 * l] =
            make_ushort4(f2bf(a0 * a0), f2bf(a1 * a1), f2bf(a2 * a2), f2bf(a3 * a3));
        *(ushort4*)&VB[(size_t)q * D + 4 * l] =
            make_ushort4(f2bf(2.0f * a0 * c0), f2bf(2.0f * a1 * c1),
                         f2bf(2.0f * a2 * c2), f2bf(2.0f * a3 * c3));

        float s = wave_sum(u0 * c0 + u1 * c1 + u2 * c2 + u3 * c3);
        if (l == 0) sq[q] = s;

        if (q == 0) {
            float ccs = wave_sum(c0 * c0 + c1 * c1 + c2 * c2 + c3 * c3);
            if (l == 0) *ccp = ccs;
        }
    }

    // ================= grid-wide barrier =================
    cg::this_grid().sync();

    // ================= Phase B: gather + MFMA =================
    const int lm = l & 15, quad = l >> 4, koff = quad * 8;
    const int q0 = (b & 15) * 16, i0 = (b >> 4) * 32;
    const int qr = q0 + lm;

    // B-frags: full K=256 for this wave's 16 query rows.
    short8 bp[8], bw[8], bv[8];
#pragma unroll
    for (int ks = 0; ks < 8; ks++) {
        const size_t o = (size_t)qr * D + ks * 32 + koff;
        bp[ks] = *(const short8*)&PB[o];
        bw[ks] = *(const short8*)&WB[o];
        bv[ks] = *(const short8*)&VB[o];
    }
    const float sqv = sq[qr];
    const float ccv = *ccp;

#pragma unroll
    for (int it = 0; it < 2; it++) {
        const int ir = i0 + it * 16 + lm;
        floatx4 acc1 = {0.f, 0.f, 0.f, 0.f};
        floatx4 acc2 = {0.f, 0.f, 0.f, 0.f};
#pragma unroll
        for (int ks = 0; ks < 8; ks++) {
            const size_t o = (size_t)ir * D + ks * 32 + koff;
            short8 ay  = *(const short8*)&YB[o];
            short8 ay2 = *(const short8*)&Y2B[o];
            acc1 = __builtin_amdgcn_mfma_f32_16x16x32_bf16(ay,  bp[ks], acc1, 0, 0, 0);
            acc2 = __builtin_amdgcn_mfma_f32_16x16x32_bf16(ay2, bw[ks], acc2, 0, 0, 0);
            acc2 = __builtin_amdgcn_mfma_f32_16x16x32_bf16(ay,  bv[ks], acc2, 0, 0, 0);
        }
        float4 o4;
        float* po = &o4.x;
#pragma unroll
        for (int rr = 0; rr < 4; rr++) {
            float nrm = fmaxf(sqrtf(fmaxf(acc2[rr] + ccv, 0.f)), 1e-12f);
            po[rr] = sigmoidf_((acc1[rr] + sqv) / nrm);
        }
        *(float4*)&out[(size_t)qr * I + i0 + it * 16 + quad * 4] = o4;
    }
}

extern "C" void kernel_launch(void* const* d_in, const int* in_sizes, int n_in,
                              void* d_out, int out_size, void* d_ws, size_t ws_size,
                              hipStream_t stream) {
    const float* qf    = (const float*)d_in[0]; // [Q,D]
    const float* qif   = (const float*)d_in[1]; // [Q,D]
    const float* gal   = (const float*)d_in[2]; // [I,D]
    const float* gamma = (const float*)d_in[3];
    const float* beta  = (const float*)d_in[4];
    const float* mean  = (const float*)d_in[5];
    const float* var   = (const float*)d_in[6];
    float* out = (float*)d_out;                 // [Q,I]

    char* base = (char*)d_ws;
    float* sq = (float*)base;                               // Q floats
    float* cc = (float*)(base + 1024);                      // 1 float
    unsigned short* PB = (unsigned short*)(base + 2048);    // Q*D bf16
    unsigned short* WB = PB + (size_t)Q * D;
    unsigned short* VB = WB + (size_t)Q * D;
    unsigned short* YB = VB + (size_t)Q * D;                // I*D bf16
    unsigned short* Y2B = YB + (size_t)I * D;

    void* args[] = {&qf, &qif, &gal, &gamma, &beta, &mean, &var,
                    &PB, &WB, &VB, &YB, &Y2B, &sq, &cc, &out};
    hipLaunchCooperativeKernel((void*)gfn_fused, dim3(1024), dim3(64),
                               args, 0, stream);
}

// Round 3
// 90.292 us; speedup vs baseline: 1.8638x; 1.8638x over previous
//
#include <hip/hip_runtime.h>
#include <math.h>

#define D 256
#define Q 256
#define I 2048

typedef __attribute__((ext_vector_type(8))) short short8;
typedef __attribute__((ext_vector_type(4))) float floatx4;

__device__ __forceinline__ float sigmoidf_(float x) {
    return 1.0f / (1.0f + expf(-x));
}

// fp32 -> bf16 round-to-nearest-even
__device__ __forceinline__ unsigned short f2bf(float f) {
    unsigned u = __float_as_uint(f);
    u += 0x7FFFu + ((u >> 16) & 1u);
    return (unsigned short)(u >> 16);
}

// Sum across the 4 lanes sharing lm (lanes lm, lm+16, lm+32, lm+48).
// Each lane owns 64 of the 256 k-columns of its row -> this completes the row.
__device__ __forceinline__ float quad_sum(float v) {
    v += __shfl_xor(v, 16, 64);
    v += __shfl_xor(v, 32, 64);
    return v;
}

// load 8 consecutive floats (two float4) into a local array
#define LOAD8(dst, src4, base)                                      \
    do {                                                            \
        float4 _a = (src4)[(base)];                                 \
        float4 _b = (src4)[(base) + 1];                             \
        (dst)[0] = _a.x; (dst)[1] = _a.y;                           \
        (dst)[2] = _a.z; (dst)[3] = _a.w;                           \
        (dst)[4] = _b.x; (dst)[5] = _b.y;                           \
        (dst)[6] = _b.z; (dst)[7] = _b.w;                           \
    } while (0)

// ONE ordinary kernel. 1024 independent 1-wave blocks, tile = 16q x 32i.
// No LDS, no __syncthreads, no grid.sync, no workspace round-trip.
//
// Redundant in-wave prep, computed directly in MFMA fragment layout:
//   lane (lm = l&15, quad = l>>4) owns q-row lm and k-cols ks*32+quad*8+e.
//   Row reductions = per-lane 64-elem partial + shfl_xor(16,32) (quad_sum).
//   B-frags bp/bw/bv (P = u*a, W = a^2, V = 2ac) packed in-register.
//   sq (= sum u*c) and cc (= sum c^2) fall out of the same reduction.
// Gallery rows normalized per it-subtile into A-frags ay/ay2 the same way.
//   acc1[i,q] = sum_k Y[i,k]  * P[q,k]
//   acc2[i,q] = sum_k Y2[i,k] * W[q,k] + Y[i,k] * V[q,k]
// Redundancy (64x query prep, 16x gallery prep) is ~0.25 us GPU-wide --
// far cheaper than the second dispatch + launch gap it replaces.
__global__ void __launch_bounds__(64, 1)
gfn_one(const float* __restrict__ qf,
        const float* __restrict__ qif,
        const float* __restrict__ gal,
        const float* __restrict__ gamma,
        const float* __restrict__ beta,
        const float* __restrict__ mean,
        const float* __restrict__ var,
        float* __restrict__ out) {
    const int l = threadIdx.x;
    const int lm = l & 15, quad = l >> 4;
    const int q0 = blockIdx.x * 16, i0 = blockIdx.y * 32;
    const int qr = q0 + lm;
    const int cb = quad * 2;   // float4 index of this lane's 8-col chunk base

    const float4* qf4  = (const float4*)qf;
    const float4* qif4 = (const float4*)qif;
    const float4* g4   = (const float4*)gal;
    const float4* ga4  = (const float4*)gamma;
    const float4* be4  = (const float4*)beta;
    const float4* me4  = (const float4*)mean;
    const float4* va4  = (const float4*)var;

    // ---------- query prep: row qr, 64 owned cols ----------
    float xx[64];                       // xq -> gate -> a
#pragma unroll
    for (int ks = 0; ks < 8; ks++)
        LOAD8(&xx[ks * 8], qf4, qr * 64 + ks * 8 + cb);
    float nx = 0.f;
#pragma unroll
    for (int e = 0; e < 64; e++) nx += xx[e] * xx[e];
    nx = quad_sum(nx);
    const float inx = 1.0f / fmaxf(sqrtf(nx), 1e-12f);
#pragma unroll
    for (int e = 0; e < 64; e++) xx[e] = sigmoidf_(xx[e] * inx * 5.0f);

    float yy[64];                       // yq -> f
#pragma unroll
    for (int ks = 0; ks < 8; ks++)
        LOAD8(&yy[ks * 8], qif4, qr * 64 + ks * 8 + cb);
    float ny = 0.f;
#pragma unroll
    for (int e = 0; e < 64; e++) ny += yy[e] * yy[e];
    ny = quad_sum(ny);
    const float iny = 1.0f / fmaxf(sqrtf(ny), 1e-12f);

    float cc_[64];                      // BN constant term c
#pragma unroll
    for (int ks = 0; ks < 8; ks++) {
        float pg[8], pb_[8], pm[8], pv[8];
        LOAD8(pg, ga4, ks * 8 + cb);
        LOAD8(pb_, be4, ks * 8 + cb);
        LOAD8(pm, me4, ks * 8 + cb);
        LOAD8(pv, va4, ks * 8 + cb);
#pragma unroll
        for (int e = 0; e < 8; e++) {
            const int j = ks * 8 + e;
            float is = pg[e] * rsqrtf(pv[e] + 1e-5f);
            float c = pb_[e] - pm[e] * is;
            float a = xx[j] * is;       // gate * inv_std
            xx[j] = a;
            yy[j] = yy[j] * iny * a + c; // f
            cc_[j] = c;
        }
    }

    float nf = 0.f;
#pragma unroll
    for (int e = 0; e < 64; e++) nf += yy[e] * yy[e];
    nf = quad_sum(nf);
    const float inf_ = 1.0f / fmaxf(sqrtf(nf), 1e-12f);

    float s = 0.f, ccs = 0.f;
#pragma unroll
    for (int e = 0; e < 64; e++) {
        float u = yy[e] * inf_;
        s += u * cc_[e];
        ccs += cc_[e] * cc_[e];
    }
    const float sqv = quad_sum(s);      // per q-row lm: sum u*c
    const float ccv = quad_sum(ccs);    // scalar: sum c^2

    // ---------- pack B-frags ----------
    short8 bp[8], bw[8], bv[8];
#pragma unroll
    for (int ks = 0; ks < 8; ks++) {
#pragma unroll
        for (int e = 0; e < 8; e++) {
            const int j = ks * 8 + e;
            float a = xx[j], c = cc_[j];
            float u = yy[j] * inf_;
            bp[ks][e] = (short)f2bf(u * a);
            bw[ks][e] = (short)f2bf(a * a);
            bv[ks][e] = (short)f2bf(2.0f * a * c);
        }
    }

    // ---------- gallery prep + MFMA, per 16-i subtile ----------
#pragma unroll
    for (int it = 0; it < 2; it++) {
        const int ir = i0 + it * 16 + lm;
        float gv[64];
#pragma unroll
        for (int ks = 0; ks < 8; ks++)
            LOAD8(&gv[ks * 8], g4, (int)(ir * 64 + ks * 8 + cb));
        float nn = 0.f;
#pragma unroll
        for (int e = 0; e < 64; e++) nn += gv[e] * gv[e];
        nn = quad_sum(nn);
        const float inv = 1.0f / fmaxf(sqrtf(nn), 1e-12f);

        short8 ay[8], ay2[8];
#pragma unroll
        for (int ks = 0; ks < 8; ks++) {
#pragma unroll
            for (int e = 0; e < 8; e++) {
                float yv = gv[ks * 8 + e] * inv;
                ay[ks][e]  = (short)f2bf(yv);
                ay2[ks][e] = (short)f2bf(yv * yv);
            }
        }

        floatx4 acc1 = {0.f, 0.f, 0.f, 0.f};
        floatx4 acc2 = {0.f, 0.f, 0.f, 0.f};
#pragma unroll
        for (int ks = 0; ks < 8; ks++) {
            acc1 = __builtin_amdgcn_mfma_f32_16x16x32_bf16(ay[ks],  bp[ks], acc1, 0, 0, 0);
            acc2 = __builtin_amdgcn_mfma_f32_16x16x32_bf16(ay2[ks], bw[ks], acc2, 0, 0, 0);
            acc2 = __builtin_amdgcn_mfma_f32_16x16x32_bf16(ay[ks],  bv[ks], acc2, 0, 0, 0);
        }

        float4 o4;
        float* po = &o4.x;
#pragma unroll
        for (int rr = 0; rr < 4; rr++) {
            float nrm = fmaxf(sqrtf(fmaxf(acc2[rr] + ccv, 0.f)), 1e-12f);
            po[rr] = sigmoidf_((acc1[rr] + sqv) / nrm);
        }
        *(float4*)&out[(size_t)qr * I + i0 + it * 16 + quad * 4] = o4;
    }
}

extern "C" void kernel_launch(void* const* d_in, const int* in_sizes, int n_in,
                              void* d_out, int out_size, void* d_ws, size_t ws_size,
                              hipStream_t stream) {
    const float* qf    = (const float*)d_in[0]; // [Q,D]
    const float* qif   = (const float*)d_in[1]; // [Q,D]
    const float* gal   = (const float*)d_in[2]; // [I,D]
    const float* gamma = (const float*)d_in[3];
    const float* beta  = (const float*)d_in[4];
    const float* mean  = (const float*)d_in[5];
    const float* var   = (const float*)d_in[6];
    float* out = (float*)d_out;                 // [Q,I]

    gfn_one<<<dim3(Q / 16, I / 32), 64, 0, stream>>>(
        qf, qif, gal, gamma, beta, mean, var, out);
}

// Round 4
// 78.843 us; speedup vs baseline: 2.1345x; 1.1452x over previous
//
#include <hip/hip_runtime.h>
#include <math.h>

#define D 256
#define Q 256
#define I 2048
#define STRIDE 264   // shorts per LDS row: 256 + 8 pad -> 2-way bank aliasing (free)

typedef __attribute__((ext_vector_type(8))) short short8;
typedef __attribute__((ext_vector_type(4))) float floatx4;

__device__ __forceinline__ float sigmoidf_(float x) {
    return 1.0f / (1.0f + expf(-x));
}

// fp32 -> bf16 round-to-nearest-even
__device__ __forceinline__ unsigned short f2bf(float f) {
    unsigned u = __float_as_uint(f);
    u += 0x7FFFu + ((u >> 16) & 1u);
    return (unsigned short)(u >> 16);
}

// sum across the 16-lane group (lanes with same l>>4)
__device__ __forceinline__ float grp16_sum(float v) {
    v += __shfl_xor(v, 1, 64);
    v += __shfl_xor(v, 2, 64);
    v += __shfl_xor(v, 4, 64);
    v += __shfl_xor(v, 8, 64);
    return v;
}

// sum across the 4 lanes sharing lm (lanes lm, lm+16, lm+32, lm+48)
__device__ __forceinline__ float quad_sum(float v) {
    v += __shfl_xor(v, 16, 64);
    v += __shfl_xor(v, 32, 64);
    return v;
}

// ONE ordinary kernel, single dispatch, no workspace.
// Grid (Q/16, I/64) = (16,32) = 512 blocks x 256 thr (4 waves). 2 blocks/CU.
//
// Phase 1 (query prep, split across waves -> 4x less serial work/thread):
//   wave w preps q-rows w*4..w*4+3; lane (grp=l>>4, lj=l&15) owns row
//   q0+w*4+grp, cols lj*16..lj*16+15. Row reductions = grp16_sum.
//   Packs P=u*a, W=a^2, V=2ac as bf16 into LDS tiles [16][STRIDE];
//   sq[row] -> LDS, cc stays uniform in-register.
// Phase 2 (per wave, 16q x 16i, K=256):
//   gallery rows iw+lm normalized in-register (quad_sum), A-frags packed,
//   B-frags read from LDS (2-way bank aliasing only).
//   acc1[i,q] = sum_k Y[i,k]*P[q,k]
//   acc2[i,q] = sum_k Y2[i,k]*W[q,k] + Y[i,k]*V[q,k]
// NO address-of-local patterns (rule #20): only float4/short8 locals with
// constant indices after full unroll -> registers, not scratch.
__global__ void __launch_bounds__(256, 2)
gfn_single(const float* __restrict__ qf,
           const float* __restrict__ qif,
           const float* __restrict__ gal,
           const float* __restrict__ gamma,
           const float* __restrict__ beta,
           const float* __restrict__ mean,
           const float* __restrict__ var,
           float* __restrict__ out) {
    __shared__ unsigned short sP[16 * STRIDE];
    __shared__ unsigned short sW[16 * STRIDE];
    __shared__ unsigned short sV[16 * STRIDE];
    __shared__ float sq_s[16];

    const int t = threadIdx.x;
    const int w = t >> 6, l = t & 63;
    const int q0 = blockIdx.x * 16, i0 = blockIdx.y * 64;

    const float4* qf4  = (const float4*)qf;
    const float4* qif4 = (const float4*)qif;
    const float4* g4   = (const float4*)gal;
    const float4* ga4  = (const float4*)gamma;
    const float4* be4  = (const float4*)beta;
    const float4* me4  = (const float4*)mean;
    const float4* va4  = (const float4*)var;

    // ================= Phase 1: query prep (4 rows/wave) =================
    const int grp = l >> 4, lj = l & 15;
    const int qrow = w * 4 + grp;          // 0..15
    const int q = q0 + qrow;

    float4 xa[4], ya[4];
#pragma unroll
    for (int m = 0; m < 4; m++) xa[m] = qf4[q * 64 + lj * 4 + m];
    float nx = 0.f;
#pragma unroll
    for (int m = 0; m < 4; m++)
        nx += xa[m].x * xa[m].x + xa[m].y * xa[m].y +
              xa[m].z * xa[m].z + xa[m].w * xa[m].w;
    nx = grp16_sum(nx);
    const float inx = 1.0f / fmaxf(sqrtf(nx), 1e-12f);
#pragma unroll
    for (int m = 0; m < 4; m++) {
        xa[m].x = sigmoidf_(xa[m].x * inx * 5.0f);
        xa[m].y = sigmoidf_(xa[m].y * inx * 5.0f);
        xa[m].z = sigmoidf_(xa[m].z * inx * 5.0f);
        xa[m].w = sigmoidf_(xa[m].w * inx * 5.0f);
    }

#pragma unroll
    for (int m = 0; m < 4; m++) ya[m] = qif4[q * 64 + lj * 4 + m];
    float ny = 0.f;
#pragma unroll
    for (int m = 0; m < 4; m++)
        ny += ya[m].x * ya[m].x + ya[m].y * ya[m].y +
              ya[m].z * ya[m].z + ya[m].w * ya[m].w;
    ny = grp16_sum(ny);
    const float iny = 1.0f / fmaxf(sqrtf(ny), 1e-12f);

    float4 av[4], cv[4], fv[4];
#pragma unroll
    for (int m = 0; m < 4; m++) {
        float4 g = ga4[lj * 4 + m], b = be4[lj * 4 + m];
        float4 mn = me4[lj * 4 + m], vr = va4[lj * 4 + m];
        float4 is, c, a, f;
        is.x = g.x * rsqrtf(vr.x + 1e-5f);
        is.y = g.y * rsqrtf(vr.y + 1e-5f);
        is.z = g.z * rsqrtf(vr.z + 1e-5f);
        is.w = g.w * rsqrtf(vr.w + 1e-5f);
        c.x = b.x - mn.x * is.x;  c.y = b.y - mn.y * is.y;
        c.z = b.z - mn.z * is.z;  c.w = b.w - mn.w * is.w;
        a.x = xa[m].x * is.x;  a.y = xa[m].y * is.y;
        a.z = xa[m].z * is.z;  a.w = xa[m].w * is.w;
        f.x = ya[m].x * iny * a.x + c.x;
        f.y = ya[m].y * iny * a.y + c.y;
        f.z = ya[m].z * iny * a.z + c.z;
        f.w = ya[m].w * iny * a.w + c.w;
        av[m] = a; cv[m] = c; fv[m] = f;
    }

    float nf = 0.f;
#pragma unroll
    for (int m = 0; m < 4; m++)
        nf += fv[m].x * fv[m].x + fv[m].y * fv[m].y +
              fv[m].z * fv[m].z + fv[m].w * fv[m].w;
    nf = grp16_sum(nf);
    const float inf_ = 1.0f / fmaxf(sqrtf(nf), 1e-12f);

    float s = 0.f, ccs = 0.f;
    short8 hp[2], hw[2], hv[2];
#pragma unroll
    for (int m = 0; m < 4; m++) {
        float4 u, a = av[m], c = cv[m];
        u.x = fv[m].x * inf_; u.y = fv[m].y * inf_;
        u.z = fv[m].z * inf_; u.w = fv[m].w * inf_;
        s   += u.x * c.x + u.y * c.y + u.z * c.z + u.w * c.w;
        ccs += c.x * c.x + c.y * c.y + c.z * c.z + c.w * c.w;
        const int h = m >> 1, e0 = (m & 1) * 4;
        hp[h][e0 + 0] = (short)f2bf(u.x * a.x);
        hp[h][e0 + 1] = (short)f2bf(u.y * a.y);
        hp[h][e0 + 2] = (short)f2bf(u.z * a.z);
        hp[h][e0 + 3] = (short)f2bf(u.w * a.w);
        hw[h][e0 + 0] = (short)f2bf(a.x * a.x);
        hw[h][e0 + 1] = (short)f2bf(a.y * a.y);
        hw[h][e0 + 2] = (short)f2bf(a.z * a.z);
        hw[h][e0 + 3] = (short)f2bf(a.w * a.w);
        hv[h][e0 + 0] = (short)f2bf(2.0f * a.x * c.x);
        hv[h][e0 + 1] = (short)f2bf(2.0f * a.y * c.y);
        hv[h][e0 + 2] = (short)f2bf(2.0f * a.z * c.z);
        hv[h][e0 + 3] = (short)f2bf(2.0f * a.w * c.w);
    }
    s = grp16_sum(s);
    const float ccv = grp16_sum(ccs);   // uniform; kept in-register
    if (lj == 0) sq_s[qrow] = s;

    const int cb = qrow * STRIDE + lj * 16;
    *(short8*)&sP[cb]     = hp[0];  *(short8*)&sP[cb + 8] = hp[1];
    *(short8*)&sW[cb]     = hw[0];  *(short8*)&sW[cb + 8] = hw[1];
    *(short8*)&sV[cb]     = hv[0];  *(short8*)&sV[cb + 8] = hv[1];

    __syncthreads();

    // ================= Phase 2: gallery + MFMA (16q x 16i per wave) =====
    const int lm = l & 15, quad = l >> 4;
    const int iw = i0 + w * 16;
    const int ir = iw + lm;

    float4 gva[16];
#pragma unroll
    for (int ks = 0; ks < 8; ks++) {
        gva[ks * 2]     = g4[ir * 64 + ks * 8 + quad * 2];
        gva[ks * 2 + 1] = g4[ir * 64 + ks * 8 + quad * 2 + 1];
    }
    float nn = 0.f;
#pragma unroll
    for (int k = 0; k < 16; k++)
        nn += gva[k].x * gva[k].x + gva[k].y * gva[k].y +
              gva[k].z * gva[k].z + gva[k].w * gva[k].w;
    nn = quad_sum(nn);
    const float inv = 1.0f / fmaxf(sqrtf(nn), 1e-12f);

    short8 ay[8], ay2[8];
#pragma unroll
    for (int ks = 0; ks < 8; ks++) {
        float4 A = gva[ks * 2], B = gva[ks * 2 + 1];
        float y0 = A.x * inv, y1 = A.y * inv, y2 = A.z * inv, y3 = A.w * inv;
        float y4 = B.x * inv, y5 = B.y * inv, y6 = B.z * inv, y7 = B.w * inv;
        ay[ks][0] = (short)f2bf(y0);  ay[ks][1] = (short)f2bf(y1);
        ay[ks][2] = (short)f2bf(y2);  ay[ks][3] = (short)f2bf(y3);
        ay[ks][4] = (short)f2bf(y4);  ay[ks][5] = (short)f2bf(y5);
        ay[ks][6] = (short)f2bf(y6);  ay[ks][7] = (short)f2bf(y7);
        ay2[ks][0] = (short)f2bf(y0 * y0);  ay2[ks][1] = (short)f2bf(y1 * y1);
        ay2[ks][2] = (short)f2bf(y2 * y2);  ay2[ks][3] = (short)f2bf(y3 * y3);
        ay2[ks][4] = (short)f2bf(y4 * y4);  ay2[ks][5] = (short)f2bf(y5 * y5);
        ay2[ks][6] = (short)f2bf(y6 * y6);  ay2[ks][7] = (short)f2bf(y7 * y7);
    }

    floatx4 acc1 = {0.f, 0.f, 0.f, 0.f};
    floatx4 acc2 = {0.f, 0.f, 0.f, 0.f};
#pragma unroll
    for (int ks = 0; ks < 8; ks++) {
        const int o = lm * STRIDE + ks * 32 + quad * 8;
        short8 bp = *(const short8*)&sP[o];
        short8 bw = *(const short8*)&sW[o];
        short8 bv = *(const short8*)&sV[o];
        acc1 = __builtin_amdgcn_mfma_f32_16x16x32_bf16(ay[ks],  bp, acc1, 0, 0, 0);
        acc2 = __builtin_amdgcn_mfma_f32_16x16x32_bf16(ay2[ks], bw, acc2, 0, 0, 0);
        acc2 = __builtin_amdgcn_mfma_f32_16x16x32_bf16(ay[ks],  bv, acc2, 0, 0, 0);
    }

    const float sqv = sq_s[lm];
    float4 o4;
    float* po = &o4.x;
#pragma unroll
    for (int rr = 0; rr < 4; rr++) {
        float nrm = fmaxf(sqrtf(fmaxf(acc2[rr] + ccv, 0.f)), 1e-12f);
        po[rr] = sigmoidf_((acc1[rr] + sqv) / nrm);
    }
    *(float4*)&out[(size_t)(q0 + lm) * I + iw + quad * 4] = o4;
}

extern "C" void kernel_launch(void* const* d_in, const int* in_sizes, int n_in,
                              void* d_out, int out_size, void* d_ws, size_t ws_size,
                              hipStream_t stream) {
    const float* qf    = (const float*)d_in[0]; // [Q,D]
    const float* qif   = (const float*)d_in[1]; // [Q,D]
    const float* gal   = (const float*)d_in[2]; // [I,D]
    const float* gamma = (const float*)d_in[3];
    const float* beta  = (const float*)d_in[4];
    const float* mean  = (const float*)d_in[5];
    const float* var   = (const float*)d_in[6];
    float* out = (float*)d_out;                 // [Q,I]

    gfn_single<<<dim3(Q / 16, I / 64), 256, 0, stream>>>(
        qf, qif, gal, gamma, beta, mean, var, out);
}